// Round 14
// baseline (37.952 us; speedup 1.0000x reference)
//
#include <hip/hip_runtime.h>
#include <hip/hip_bf16.h>
#include <math.h>

// MACE equivariant score head — 2-kernel form: {D-blocks ∥ M-blocks w/ partial
// fence} + MFMA K4.
// Dead code: Wss (d_in[5]), Wvv (d_in[7]) — s3=silu(s2) is deleted in the reference.
// out[n,m] = sum_c vraw[n,c,m] * h[n,c]
// h[n,c]   = t[n]*b[c] + sum_q feat[n,q] * M[q,c]
//   D[u,v] = dot(Wsv[u,v,:], W2); F[v] = sum_u wrow[u] D[u,v]
//   M[q,c] = scale * sum_v F[v] * W1v[c,v],  scale = 1/(S*V*sqrt(V))
//
// k1: 273 blocks, 69.4KB LDS each -> 2 blocks/CU -> 512 slots >= 273: ALL
//     co-resident under any packing => the one-way spin cannot deadlock.
//   [0,144):  D-block u — stream 64KB slab Wsv[u,:,:] (regs), butterfly-reduce,
//             write D[u,:], then release: __syncthreads (drains vmcnt) +
//             tid0 {__threadfence (L2 writeback), agent-scope atomicAdd}.
//             (Exact protocol validated in R6 across graph replays.)
//   [144,273): M-block q — stage W1v->LDS + wrow (independent of D, overlaps
//             the D stream), then tid0 spins on the counter (acquire fence),
//             then R13's verified K23 body: F-GEMV + M-row in bf16^T + b.
// k4: byte-identical to R13's verified MFMA kernel.

#define S 144
#define V 128

typedef __attribute__((ext_vector_type(8))) short bf16x8;
typedef __attribute__((ext_vector_type(4))) float f32x4;

// ---------------- k1: D-blocks + fenced M-blocks ----------------
__global__ __launch_bounds__(256) void k1_DM(const float* __restrict__ Wsv,
                                             const float* __restrict__ W2,
                                             const float* __restrict__ W1s,
                                             const float* __restrict__ W1v,
                                             const float* __restrict__ Wt,
                                             float* __restrict__ D,
                                             unsigned short* __restrict__ Mt,
                                             float* __restrict__ b,
                                             unsigned* __restrict__ cnt) {
    __shared__ float w1v[V * 129];     // 66 KB (M-path; D-path leaves it unused)
    __shared__ float wrow[S];
    __shared__ float Fpart[4][V];
    __shared__ float Fsh[V];
    const int tid = threadIdx.x;
    const int wave = tid >> 6;
    const int lane = tid & 63;

    if (blockIdx.x < S) {
        // ---- D-block: u = blockIdx.x ----
        const int half = lane >> 5;          // row within pair
        const int j = lane & 31;             // float4 index within 128-float row
        const int u = blockIdx.x;
        const float4* Wsv4 = (const float4*)Wsv;
        const float4 w4 = ((const float4*)W2)[j];
        const size_t base4 = ((size_t)u * V + 32 * wave) * 32;
        float4 a[16];
#pragma unroll
        for (int i = 0; i < 16; ++i)
            a[i] = Wsv4[base4 + (size_t)(2 * i + half) * 32 + j];
#pragma unroll
        for (int i = 0; i < 16; ++i) {
            float acc = a[i].x * w4.x + a[i].y * w4.y + a[i].z * w4.z + a[i].w * w4.w;
#pragma unroll
            for (int off = 1; off < 32; off <<= 1)
                acc += __shfl_xor(acc, off, 64);   // width-32: stays in half
            if (j == 0) D[u * V + 32 * wave + 2 * i + half] = acc;
        }
        // release: all waves drain vmcnt at the barrier, then one L2 writeback
        __syncthreads();
        if (tid == 0) {
            __threadfence();
            __hip_atomic_fetch_add(cnt, 1u, __ATOMIC_ACQ_REL, __HIP_MEMORY_SCOPE_AGENT);
        }
    } else {
        // ---- M-block: q = blockIdx.x - S ----
        const int q = blockIdx.x - S;

        // (1) stage W1v padded + wrow — independent of D, overlaps D stream
        {
            const float4* W1v4 = (const float4*)W1v;
            for (int i = tid; i < V * V / 4; i += 256) {
                const float4 t = W1v4[i];
                const int base = i * 4;
                float* dst = &w1v[(base >> 7) * 129 + (base & 127)];
                dst[0] = t.x; dst[1] = t.y; dst[2] = t.z; dst[3] = t.w;
            }
        }
        if (tid < S) {
            if (q < V) {
                wrow[tid] = W1s[(16 + q) * S + tid];
            } else {
                float acc = 0.f;
#pragma unroll
                for (int p = 0; p < 16; ++p)
                    acc = fmaf(Wt[p], W1s[p * S + tid], acc);
                wrow[tid] = acc;
            }
        }
        __syncthreads();

        // (2) acquire: wait for all 144 D-blocks
        if (tid == 0) {
            while (__hip_atomic_load(cnt, __ATOMIC_ACQUIRE, __HIP_MEMORY_SCOPE_AGENT) < (unsigned)S)
                __builtin_amdgcn_s_sleep(2);
            __threadfence();     // invalidate stale L2 lines before D reads
        }
        __syncthreads();

        // (3) F[v] = sum_u wrow[u]*D[u,v]; wave w: u in [36w,36w+36), lane t -> v=2t,2t+1
        {
            const int w = tid >> 6, t = tid & 63;
            float fx = 0.f, fy = 0.f;
#pragma unroll 6
            for (int u = 36 * w; u < 36 * w + 36; ++u) {
                const float wr = wrow[u];
                const float2 dv = *(const float2*)&D[u * V + 2 * t];
                fx = fmaf(wr, dv.x, fx);
                fy = fmaf(wr, dv.y, fy);
            }
            Fpart[w][2 * t + 0] = fx;
            Fpart[w][2 * t + 1] = fy;
        }
        __syncthreads();
        if (tid < V)
            Fsh[tid] = (Fpart[0][tid] + Fpart[1][tid]) + (Fpart[2][tid] + Fpart[3][tid]);
        __syncthreads();

        // (4) row of M (bf16, transposed) or b
        if (tid < V) {
            const float scale = 1.0f / (144.0f * 128.0f * sqrtf(128.0f));
            float m0 = 0.f, m1 = 0.f, m2 = 0.f, m3 = 0.f;
#pragma unroll 8
            for (int v = 0; v < V; v += 4) {
                m0 = fmaf(Fsh[v + 0], w1v[tid * 129 + v + 0], m0);
                m1 = fmaf(Fsh[v + 1], w1v[tid * 129 + v + 1], m1);
                m2 = fmaf(Fsh[v + 2], w1v[tid * 129 + v + 2], m2);
                m3 = fmaf(Fsh[v + 3], w1v[tid * 129 + v + 3], m3);
            }
            const float r = ((m0 + m1) + (m2 + m3)) * scale;
            if (q < V) {
                const __hip_bfloat16 h = __float2bfloat16(r);
                Mt[tid * V + q] = *(const unsigned short*)&h;   // transposed bf16
            } else {
                b[tid] = r;
            }
        }
    }
}

// ---------------- K4: MFMA h-GEMM + epilogue (verified R13) ----------------
__global__ __launch_bounds__(256) void k4_mfma(const float* __restrict__ feat,
                                               const float* __restrict__ times,
                                               const unsigned short* __restrict__ Mtg,
                                               const float* __restrict__ bg,
                                               float* __restrict__ out) {
    __shared__ unsigned short Msh[V][136];   // bf16, +8 bf16 (16B) row pad
    __shared__ unsigned short srow[16][136]; // bf16 s rows, same pad
    __shared__ float tsh[16];
    __shared__ float red[4][16][3];
    const int tid = threadIdx.x;
    const int wave = tid >> 6;
    const int lane = tid & 63;
    const int n0 = blockIdx.x * 16;

    // stage Mt (16384 bf16 = 2048 uint4), 8 uint4/thread, into padded rows
    {
        const uint4* src = (const uint4*)Mtg;
#pragma unroll
        for (int i = 0; i < 8; ++i) {
            const int idx = tid + 256 * i;       // uint4 index
            const int r = idx >> 4;              // 16 uint4 per 128-bf16 row
            const int c8 = (idx & 15) * 8;       // bf16 col
            *(uint4*)&Msh[r][c8] = src[idx];
        }
    }
    // stage s rows as bf16: thread -> row tid>>4, q0 = (tid&15)*8
    {
        const int r = tid >> 4, q0 = (tid & 15) * 8;
        const float* p = feat + (size_t)(n0 + r) * 512 + q0;
        const float4 f0 = *(const float4*)(p);
        const float4 f1 = *(const float4*)(p + 4);
        __hip_bfloat162 p0 = __float22bfloat162_rn(make_float2(f0.x, f0.y));
        __hip_bfloat162 p1 = __float22bfloat162_rn(make_float2(f0.z, f0.w));
        __hip_bfloat162 p2 = __float22bfloat162_rn(make_float2(f1.x, f1.y));
        __hip_bfloat162 p3 = __float22bfloat162_rn(make_float2(f1.z, f1.w));
        uint4 pk;
        pk.x = *(const unsigned*)&p0;
        pk.y = *(const unsigned*)&p1;
        pk.z = *(const unsigned*)&p2;
        pk.w = *(const unsigned*)&p3;
        *(uint4*)&srow[r][q0] = pk;
    }
    if (tid < 16) tsh[tid] = times[n0 + tid];
    // per-lane bias values for its two c's
    const int mrow = lane & 15;     // A-row / B-col within tile / C-col
    const int kch = lane >> 4;      // k-chunk 0..3
    const float bc0 = bg[32 * wave + mrow];
    const float bc1 = bg[32 * wave + 16 + mrow];
    __syncthreads();

    // MFMA: A = s[16 x 128], B = M[128 x 128] restricted to wave's 32 cols
    f32x4 acc0 = {0.f, 0.f, 0.f, 0.f};
    f32x4 acc1 = {0.f, 0.f, 0.f, 0.f};
#pragma unroll
    for (int kk = 0; kk < 4; ++kk) {
        const bf16x8 af = *(const bf16x8*)&srow[mrow][kk * 32 + kch * 8];
        const bf16x8 bf0 = *(const bf16x8*)&Msh[32 * wave + mrow][kk * 32 + kch * 8];
        const bf16x8 bf1 = *(const bf16x8*)&Msh[32 * wave + 16 + mrow][kk * 32 + kch * 8];
        acc0 = __builtin_amdgcn_mfma_f32_16x16x32_bf16(af, bf0, acc0, 0, 0, 0);
        acc1 = __builtin_amdgcn_mfma_f32_16x16x32_bf16(af, bf1, acc1, 0, 0, 0);
    }

    // epilogue: lane holds h[n=(lane>>4)*4+i][c0=32w+mrow] (acc0) and c1=c0+16 (acc1)
    float pm[4][3];
#pragma unroll
    for (int i = 0; i < 4; ++i) {
        const int nr = kch * 4 + i;
        const float t = tsh[nr];
        const float h0 = acc0[i] + t * bc0;
        const float h1 = acc1[i] + t * bc1;
        const float* vp0 = feat + (size_t)(n0 + nr) * 512 + V + 3 * (32 * wave + mrow);
        const float* vp1 = vp0 + 48;   // c1 = c0 + 16 -> +48 floats
#pragma unroll
        for (int m = 0; m < 3; ++m)
            pm[i][m] = vp0[m] * h0 + vp1[m] * h1;
    }
    // reduce over the 16-lane c-group (offsets < 16 stay in group)
#pragma unroll
    for (int i = 0; i < 4; ++i) {
#pragma unroll
        for (int m = 0; m < 3; ++m) {
            float v = pm[i][m];
            v += __shfl_xor(v, 1, 64);
            v += __shfl_xor(v, 2, 64);
            v += __shfl_xor(v, 4, 64);
            v += __shfl_xor(v, 8, 64);
            pm[i][m] = v;
        }
        if (mrow == 0) {
            const int nr = kch * 4 + i;
            red[wave][nr][0] = pm[i][0];
            red[wave][nr][1] = pm[i][1];
            red[wave][nr][2] = pm[i][2];
        }
    }
    __syncthreads();
    // sum the 4 wave-partials (c-blocks) and write out
    if (tid < 48) {
        const int nr = tid / 3, m = tid % 3;
        out[(size_t)(n0 + nr) * 3 + m] =
            red[0][nr][m] + red[1][nr][m] + red[2][nr][m] + red[3][nr][m];
    }
}

extern "C" void kernel_launch(void* const* d_in, const int* in_sizes, int n_in,
                              void* d_out, int out_size, void* d_ws, size_t ws_size,
                              hipStream_t stream) {
    const float* feat  = (const float*)d_in[0];  // [4096, 512]
    const float* times = (const float*)d_in[1];  // [4096, 1]
    const float* Wt    = (const float*)d_in[2];  // [1,16]
    const float* W1s   = (const float*)d_in[3];  // [144,144]
    const float* W1v   = (const float*)d_in[4];  // [128,128]
    // d_in[5] = Wss  -- dead path
    const float* Wsv   = (const float*)d_in[6];  // [144,128,128]
    // d_in[7] = Wvv  -- dead path
    const float* W2    = (const float*)d_in[8];  // [128,1]

    float* ws = (float*)d_ws;
    float* D  = ws;                                     // 18432 f32
    unsigned short* Mt = (unsigned short*)(ws + 18432); // 16384 bf16 (8192 f32 slots)
    float* b  = ws + 18432 + 8192;                      // 128 f32
    unsigned* cnt = (unsigned*)(ws + 18432 + 8192 + 128);

    hipMemsetAsync(cnt, 0, sizeof(unsigned), stream);   // graph-capture-safe (R6)

    k1_DM<<<dim3(273), dim3(256), 0, stream>>>(Wsv, W2, W1s, W1v, Wt, D, Mt, b, cnt);
    k4_mfma<<<dim3(256), dim3(256), 0, stream>>>(feat, times, Mt, b, (float*)d_out);
}

// Round 16
// 17.617 us; speedup vs baseline: 2.1543x; 2.1543x over previous
//
#include <hip/hip_runtime.h>
#include <hip/hip_bf16.h>
#include <math.h>

// MACE equivariant score head — 2 nodes, NO fences/atomics. v2 of R15:
//   + __syncthreads() between M-GEMM and h-GEMM (kills LDS ordering hazard)
//   + Ash rows 129..143 zero-filled (no garbage into MFMA)
// Dead code: Wss (d_in[5]), Wvv (d_in[7]) — s3=silu(s2) is deleted in the reference.
//
// out[n,m] = sum_c vraw[n,c,m] * h[n,c]
// h[n,c]   = t[n]*b[c] + sum_q s[n,q] * M[q,c]
//   E[u,c] = scale * sum_v D[u,v] * W1v[c,v],  D[u,v] = dot(Wsv[u,v,:], W2)
//   M[q,c] = sum_u W~aug[q,u] * E[u,c]   (q=0..127: W1s[16+q,u]; q=128 row -> b)
//   scale  = 1/(S*V*sqrt(V))

#define S 144
#define V 128

typedef __attribute__((ext_vector_type(8))) short bf16x8;
typedef __attribute__((ext_vector_type(4))) float f32x4;

// ---------------- kE: Et[c][u] (bf16) from Wsv slab u ----------------
__global__ __launch_bounds__(256) void kE(const float* __restrict__ Wsv,
                                          const float* __restrict__ W2,
                                          const float* __restrict__ W1v,
                                          unsigned short* __restrict__ Et) {
    __shared__ float Dsh[V];
    __shared__ float Epart[2][V];
    const int tid = threadIdx.x;
    const int wave = tid >> 6;
    const int lane = tid & 63;
    const int half = lane >> 5;
    const int j = lane & 31;
    const int u = blockIdx.x;

    const float4* Wsv4 = (const float4*)Wsv;
    const float4 w4 = ((const float4*)W2)[j];
    const size_t base4 = ((size_t)u * V + 32 * wave) * 32;
    float4 a[16];
#pragma unroll
    for (int i = 0; i < 16; ++i)
        a[i] = Wsv4[base4 + (size_t)(2 * i + half) * 32 + j];
#pragma unroll
    for (int i = 0; i < 16; ++i) {
        float acc = a[i].x * w4.x + a[i].y * w4.y + a[i].z * w4.z + a[i].w * w4.w;
#pragma unroll
        for (int off = 1; off < 32; off <<= 1)
            acc += __shfl_xor(acc, off, 64);
        if (j == 0) Dsh[32 * wave + 2 * i + half] = acc;
    }
    __syncthreads();

    const int c = tid & 127, vh = tid >> 7;
    const float4* W1v4 = (const float4*)W1v;
    const float4* D4 = (const float4*)Dsh;
    float acc = 0.f;
#pragma unroll
    for (int i = 0; i < 16; ++i) {
        const float4 wv = W1v4[c * 32 + vh * 16 + i];
        const float4 dv = D4[vh * 16 + i];
        acc += wv.x * dv.x + wv.y * dv.y + wv.z * dv.z + wv.w * dv.w;
    }
    Epart[vh][c] = acc;
    __syncthreads();
    if (tid < V) {
        const float scale = 1.0f / (144.0f * 128.0f * sqrtf(128.0f));
        const float val = scale * (Epart[0][tid] + Epart[1][tid]);
        const __hip_bfloat16 hb = __float2bfloat16(val);
        Et[(size_t)tid * S + u] = *(const unsigned short*)&hb;   // [c][u]
    }
}

// ---------------- k4b: per-block M-GEMM + h-GEMM + epilogue ----------------
__global__ __launch_bounds__(256) void k4b(const float* __restrict__ feat,
                                           const float* __restrict__ times,
                                           const float* __restrict__ Wt,
                                           const float* __restrict__ W1s,
                                           const unsigned short* __restrict__ EtG,
                                           float* __restrict__ out) {
    __shared__ unsigned short Ash[144][168];   // W~aug[q][u], K-pad zeros
    __shared__ unsigned short Etsh[128][168];  // Et[c][u], K-pad zeros
    __shared__ unsigned short Mtsh[128][136];  // M^T[c][q]
    __shared__ unsigned short srow[16][136];   // bf16 s rows
    __shared__ float bsh[128];
    __shared__ float tsh[16];
    __shared__ float red[4][16][3];
    const int tid = threadIdx.x;
    const int wave = tid >> 6;
    const int lane = tid & 63;
    const int n0 = blockIdx.x * 16;
    const int mrow = lane & 15;
    const int kch = lane >> 4;

    // --- stage W~ rows 0..127: 4608 float4 / 256 thr = 18 each ---
#pragma unroll
    for (int i = 0; i < 18; ++i) {
        const int idx = tid + 256 * i;
        const int row = idx / 36;
        const int c4 = (idx % 36) * 4;
        const float4 f = *(const float4*)(W1s + (size_t)(16 + row) * S + c4);
        const __hip_bfloat162 p0 = __float22bfloat162_rn(make_float2(f.x, f.y));
        const __hip_bfloat162 p1 = __float22bfloat162_rn(make_float2(f.z, f.w));
        uint2 pk;
        pk.x = *(const unsigned*)&p0;
        pk.y = *(const unsigned*)&p1;
        *(uint2*)&Ash[row][c4] = pk;
    }
    // --- row 128 = wtld[u] ---
    if (tid < S) {
        float a = 0.f;
#pragma unroll
        for (int p = 0; p < 16; ++p)
            a = fmaf(Wt[p], W1s[p * S + tid], a);
        const __hip_bfloat16 hb = __float2bfloat16(a);
        Ash[128][tid] = *(const unsigned short*)&hb;
    }
    // --- zero K-pad cols 144..167 (Ash rows 0..128, Etsh rows 0..127) ---
    for (int i = tid; i < 864; i += 256) {
        const int row = i / 6, c4 = 144 + (i % 6) * 4;
        *(unsigned long long*)&Ash[row][c4] = 0ULL;
    }
    for (int i = tid; i < 768; i += 256) {
        const int row = i / 6, c4 = 144 + (i % 6) * 4;
        *(unsigned long long*)&Etsh[row][c4] = 0ULL;
    }
    // --- zero Ash rows 129..143 entirely (15 rows x 21 uint4) ---
    {
        const uint4 z4 = {0u, 0u, 0u, 0u};
        for (int i = tid; i < 315; i += 256) {
            const int row = 129 + i / 21;
            const int c8 = (i % 21) * 8;
            *(uint4*)&Ash[row][c8] = z4;
        }
    }
    // --- stage Et: 2304 uint4 / 256 thr = 9 each ---
    {
        const uint4* src = (const uint4*)EtG;
#pragma unroll
        for (int i = 0; i < 9; ++i) {
            const int idx = tid + 256 * i;
            const int row = idx / 18;            // c
            const int c8 = (idx % 18) * 8;       // u
            *(uint4*)&Etsh[row][c8] = src[idx];
        }
    }
    // --- stage s rows as bf16 (R13) ---
    {
        const int r = tid >> 4, q0 = (tid & 15) * 8;
        const float* p = feat + (size_t)(n0 + r) * 512 + q0;
        const float4 f0 = *(const float4*)(p);
        const float4 f1 = *(const float4*)(p + 4);
        const __hip_bfloat162 p0 = __float22bfloat162_rn(make_float2(f0.x, f0.y));
        const __hip_bfloat162 p1 = __float22bfloat162_rn(make_float2(f0.z, f0.w));
        const __hip_bfloat162 p2 = __float22bfloat162_rn(make_float2(f1.x, f1.y));
        const __hip_bfloat162 p3 = __float22bfloat162_rn(make_float2(f1.z, f1.w));
        uint4 pk;
        pk.x = *(const unsigned*)&p0;
        pk.y = *(const unsigned*)&p1;
        pk.z = *(const unsigned*)&p2;
        pk.w = *(const unsigned*)&p3;
        *(uint4*)&srow[r][q0] = pk;
    }
    if (tid < 16) tsh[tid] = times[n0 + tid];
    __syncthreads();

    // --- GEMM-M: M[q][c] = sum_u Ash[q][u]*Etsh[c][u], wave w -> c in [32w,32w+32) ---
    bf16x8 Bf[2][5];
#pragma unroll
    for (int c2 = 0; c2 < 2; ++c2)
#pragma unroll
        for (int kk = 0; kk < 5; ++kk)
            Bf[c2][kk] = *(const bf16x8*)&Etsh[(2 * wave + c2) * 16 + mrow][kk * 32 + kch * 8];

#pragma unroll
    for (int rt = 0; rt < 9; ++rt) {
        bf16x8 Af[5];
#pragma unroll
        for (int kk = 0; kk < 5; ++kk)
            Af[kk] = *(const bf16x8*)&Ash[rt * 16 + mrow][kk * 32 + kch * 8];
#pragma unroll
        for (int c2 = 0; c2 < 2; ++c2) {
            f32x4 acc = {0.f, 0.f, 0.f, 0.f};
#pragma unroll
            for (int kk = 0; kk < 5; ++kk)
                acc = __builtin_amdgcn_mfma_f32_16x16x32_bf16(Af[kk], Bf[c2][kk], acc, 0, 0, 0);
            const int c = (2 * wave + c2) * 16 + mrow;
            if (rt < 8) {
#pragma unroll
                for (int i = 0; i < 4; ++i) {
                    const int q = rt * 16 + kch * 4 + i;
                    const __hip_bfloat16 hb = __float2bfloat16(acc[i]);
                    Mtsh[c][q] = *(const unsigned short*)&hb;
                }
            } else if (kch == 0) {
                bsh[c] = acc[0];      // q = 128 row -> b[c], f32
            }
        }
    }
    __syncthreads();   // make all Mtsh/bsh writes visible — removes ordering hazard

    // --- h-GEMM (R13 verbatim, Mtsh/bsh sources) ---
    const float bc0 = bsh[32 * wave + mrow];
    const float bc1 = bsh[32 * wave + 16 + mrow];
    f32x4 acc0 = {0.f, 0.f, 0.f, 0.f};
    f32x4 acc1 = {0.f, 0.f, 0.f, 0.f};
#pragma unroll
    for (int kk = 0; kk < 4; ++kk) {
        const bf16x8 af = *(const bf16x8*)&srow[mrow][kk * 32 + kch * 8];
        const bf16x8 bf0 = *(const bf16x8*)&Mtsh[32 * wave + mrow][kk * 32 + kch * 8];
        const bf16x8 bf1 = *(const bf16x8*)&Mtsh[32 * wave + 16 + mrow][kk * 32 + kch * 8];
        acc0 = __builtin_amdgcn_mfma_f32_16x16x32_bf16(af, bf0, acc0, 0, 0, 0);
        acc1 = __builtin_amdgcn_mfma_f32_16x16x32_bf16(af, bf1, acc1, 0, 0, 0);
    }

    float pm[4][3];
#pragma unroll
    for (int i = 0; i < 4; ++i) {
        const int nr = kch * 4 + i;
        const float t = tsh[nr];
        const float h0 = acc0[i] + t * bc0;
        const float h1 = acc1[i] + t * bc1;
        const float* vp0 = feat + (size_t)(n0 + nr) * 512 + V + 3 * (32 * wave + mrow);
        const float* vp1 = vp0 + 48;
#pragma unroll
        for (int m = 0; m < 3; ++m)
            pm[i][m] = vp0[m] * h0 + vp1[m] * h1;
    }
#pragma unroll
    for (int i = 0; i < 4; ++i) {
#pragma unroll
        for (int m = 0; m < 3; ++m) {
            float v = pm[i][m];
            v += __shfl_xor(v, 1, 64);
            v += __shfl_xor(v, 2, 64);
            v += __shfl_xor(v, 4, 64);
            v += __shfl_xor(v, 8, 64);
            pm[i][m] = v;
        }
        if (mrow == 0) {
            const int nr = kch * 4 + i;
            red[wave][nr][0] = pm[i][0];
            red[wave][nr][1] = pm[i][1];
            red[wave][nr][2] = pm[i][2];
        }
    }
    __syncthreads();
    if (tid < 48) {
        const int nr = tid / 3, m = tid % 3;
        out[(size_t)(n0 + nr) * 3 + m] =
            red[0][nr][m] + red[1][nr][m] + red[2][nr][m] + red[3][nr][m];
    }
}

extern "C" void kernel_launch(void* const* d_in, const int* in_sizes, int n_in,
                              void* d_out, int out_size, void* d_ws, size_t ws_size,
                              hipStream_t stream) {
    const float* feat  = (const float*)d_in[0];  // [4096, 512]
    const float* times = (const float*)d_in[1];  // [4096, 1]
    const float* Wt    = (const float*)d_in[2];  // [1,16]
    const float* W1s   = (const float*)d_in[3];  // [144,144]
    const float* W1v   = (const float*)d_in[4];  // [128,128]
    // d_in[5] = Wss  -- dead path
    const float* Wsv   = (const float*)d_in[6];  // [144,128,128]
    // d_in[7] = Wvv  -- dead path
    const float* W2    = (const float*)d_in[8];  // [128,1]

    unsigned short* Et = (unsigned short*)d_ws;   // [128][144] bf16

    kE<<<dim3(144), dim3(256), 0, stream>>>(Wsv, W2, W1v, Et);
    k4b<<<dim3(256), dim3(256), 0, stream>>>(feat, times, Wt, W1s, Et, (float*)d_out);
}